// Round 14
// baseline (277.398 us; speedup 1.0000x reference)
//
#include <hip/hip_runtime.h>
#include <hip/hip_bf16.h>

typedef __bf16 bf16x8 __attribute__((ext_vector_type(8)));
typedef float f32x4 __attribute__((ext_vector_type(4)));
typedef unsigned short u16x8 __attribute__((ext_vector_type(8)));

static __device__ __forceinline__ unsigned short f2bf(float f){
  unsigned int u = __float_as_uint(f);
  u += 0x7fffu + ((u >> 16) & 1u);   // round-to-nearest-even
  return (unsigned short)(u >> 16);
}

static __device__ __forceinline__ u16x8 cvt8(const float4& a, const float4& b){
  u16x8 r;
  r[0]=f2bf(a.x); r[1]=f2bf(a.y); r[2]=f2bf(a.z); r[3]=f2bf(a.w);
  r[4]=f2bf(b.x); r[5]=f2bf(b.y); r[6]=f2bf(b.z); r[7]=f2bf(b.w);
  return r;
}

static __device__ __forceinline__ void gload16(const void* g, void* l){
  __builtin_amdgcn_global_load_lds(
      (const __attribute__((address_space(1))) unsigned int*)g,
      (__attribute__((address_space(3))) unsigned int*)l, 16, 0, 0);
}

// T1: XCD-aware bijective block remap (m204 variant) — r13-verified: FETCH −65%.
static __device__ __forceinline__ int xcd_remap(int o, int nwg){
  const int NX = 8;
  int q = nwg / NX, r = nwg % NX;
  int xcd = o % NX, pos = o / NX;
  return (xcd < r ? xcd * (q + 1) : r * (q + 1) + (xcd - r) * q) + pos;
}

// ---------------- pipelined bf16 GEMM: C[m,n] = epi( sum_k A[m,k]*B[n,k] )
// A:[M][K] bf16, B:[N][K] bf16, row-major. BM=BN=128, BK=32, 4 waves (2x2 of 64x64).
// r6-verified schedule + r14 change: MFMAs issue DIRECTLY after ds_reads (no forced
// lgkmcnt(0)/sched_barrier between them) so the compiler emits fine-grained
// lgkmcnt(N) and MFMA overlaps LDS-read latency. Drain+barrier+stage moved after.
// EPI 0: Cf = acc + bias(optional)  EPI 1: atomicAdd(Cf, acc)  EPI 2: Cbf = bf16(tanh(acc+bias))
template<int EPI>
__global__ __launch_bounds__(256) void gemm_bf(
    const unsigned short* __restrict__ A, const unsigned short* __restrict__ Bw,
    const float* __restrict__ bias,
    float* __restrict__ Cf, unsigned short* __restrict__ Cbf,
    int M, int N, int K, int kchunk)
{
  constexpr int BM = 128, BN = 128, BK = 32, BUF = (BM + BN) * BK;
  __shared__ unsigned short lds[3 * BUF];             // 3 x 16 KB

  // T1 remap: consecutive logical ids (fastest dim = x) chunked per XCD
  const int gx = gridDim.x, gy = gridDim.y;
  const int nwg = gx * gy * gridDim.z;
  int o = blockIdx.x + gx * (blockIdx.y + gy * blockIdx.z);
  int v = xcd_remap(o, nwg);
  const int bx = v % gx; v /= gx;
  const int by = v % gy; const int bz = v / gy;

  const int tid  = threadIdx.x, lane = tid & 63, wave = tid >> 6;
  const int bm0  = by * BM, bn0 = bx * BN;
  const int k0   = bz * kchunk;
  const int kend = min(K, k0 + kchunk);               // kchunk multiple of 32 everywhere
  const int fr = lane & 15, fq = lane >> 4;
  const int wm = (wave >> 1) * 64, wn = (wave & 1) * 64;

  // staging: waves 0,1 -> A chunks 0..3 / 4..7; waves 2,3 -> B likewise.
  // chunk = 1KB = 16 rows of [128][32] bf16; lane l -> dest base + l*16
  const bool isA  = wave < 2;
  const int cbase = (wave & 1) * 4;
  const int srow  = lane >> 2, scol = (lane & 3) * 8;
  const unsigned short* G = isA ? A : Bw;
  const int glim = (isA ? M : N) - 1;
  const int g0   = isA ? bm0 : bn0;
  const int loff = isA ? 0 : BM * BK;

  const int nk = (kend - k0) / BK;                    // exact (kchunk mult of 32)

  auto stage = [&](int buf, int t){
    unsigned short* dst = lds + buf * BUF + loff;
    const int kk = k0 + t * BK;
    #pragma unroll
    for (int c = 0; c < 4; c++) {
      const int ch = cbase + c;
      const int r = min(g0 + ch * 16 + srow, glim);   // clamp; epilogue masks
      gload16(G + (size_t)r * K + kk + scol, (char*)dst + ch * 1024);
    }
  };

  if (nk > 0) stage(0, 0);
  if (nk > 1) stage(1, 1);
  if (nk > 2) stage(2, 2);

  f32x4 acc[4][4] = {};
  int cur = 0;                                        // = t % 3

  for (int t = 0; t < nk; ++t) {
    const int rem = nk - t - 1;                       // stages in flight beyond t
    if (rem >= 2)      asm volatile("s_waitcnt vmcnt(8)" ::: "memory");
    else if (rem == 1) asm volatile("s_waitcnt vmcnt(4)" ::: "memory");
    else               asm volatile("s_waitcnt vmcnt(0)" ::: "memory");
    __builtin_amdgcn_s_barrier();                     // tile t visible to all waves
    __builtin_amdgcn_sched_barrier(0);

    const unsigned short* lA = lds + cur * BUF;
    const unsigned short* lB = lA + BM * BK;
    u16x8 af[4], bg[4];
    #pragma unroll
    for (int i = 0; i < 4; i++) af[i] = *(const u16x8*)&lA[(wm + i*16 + fr) * BK + fq * 8];
    #pragma unroll
    for (int j = 0; j < 4; j++) bg[j] = *(const u16x8*)&lB[(wn + j*16 + fr) * BK + fq * 8];

    // MFMAs directly after the reads: compiler inserts counted lgkmcnt(N) waits,
    // overlapping MFMA issue with LDS-read completion (r14 change).
    #pragma unroll
    for (int i = 0; i < 4; i++)
      #pragma unroll
      for (int j = 0; j < 4; j++)
        acc[i][j] = __builtin_amdgcn_mfma_f32_16x16x32_bf16(
            __builtin_bit_cast(bf16x8, af[i]),
            __builtin_bit_cast(bf16x8, bg[j]),
            acc[i][j], 0, 0, 0);

    asm volatile("s_waitcnt lgkmcnt(0)" ::: "memory"); // no-op by now (all frags consumed)
    __builtin_amdgcn_sched_barrier(0);
    __builtin_amdgcn_s_barrier();                      // all waves done reading buf cur
    if (t + 3 < nk) stage(cur, t + 3);                 // refill freed buffer
    cur = (cur == 2) ? 0 : cur + 1;
  }

  #pragma unroll
  for (int i = 0; i < 4; i++)
    #pragma unroll
    for (int j = 0; j < 4; j++)
      #pragma unroll
      for (int r = 0; r < 4; r++) {
        int row = bm0 + wm + i*16 + fq*4 + r;
        int col = bn0 + wn + j*16 + fr;
        if (row < M && col < N) {
          float v2 = acc[i][j][r];
          if constexpr (EPI == 0) {
            Cf[(size_t)row * N + col] = v2 + (bias ? bias[col] : 0.0f);
          } else if constexpr (EPI == 1) {
            atomicAdd(&Cf[(size_t)row * N + col], v2);
          } else {
            Cbf[(size_t)row * N + col] = f2bf(tanhf(v2 + bias[col]));
          }
        }
      }
}

// ------- fp32 -> bf16 conversion (4 flat segments), grid-stride, 16 elems/thread ------
__global__ __launch_bounds__(256) void cvt4_kernel(
    const float* __restrict__ s0, unsigned short* __restrict__ d0, int n0,
    const float* __restrict__ s1, unsigned short* __restrict__ d1, int n1,
    const float* __restrict__ s2, unsigned short* __restrict__ d2, int n2,
    const float* __restrict__ s3, unsigned short* __restrict__ d3, int n3,
    int nunits16)
{
  const int stride = gridDim.x * 256;
  for (int u = blockIdx.x * 256 + threadIdx.x; u < nunits16; u += stride) {
    int i = u * 16;
    const float* s; unsigned short* d;
    if (i < n0)              { s = s0; d = d0; }
    else if ((i -= n0) < n1) { s = s1; d = d1; }
    else if ((i -= n1) < n2) { s = s2; d = d2; }
    else                     { i -= n2; s = s3; d = d3; }
    const float4* q = (const float4*)(s + i);
    float4 a0 = q[0], a1 = q[1], a2 = q[2], a3 = q[3];   // 4 independent 16B loads
    *(u16x8*)(d + i)     = cvt8(a0, a1);
    *(u16x8*)(d + i + 8) = cvt8(a2, a3);
  }
}

// fp32 [rows][scols] -> bf16 [rows][dcols], zero-padded (dcols mult of 8)
__global__ __launch_bounds__(256) void cvtpad_kernel(
    const float* __restrict__ src, unsigned short* __restrict__ dst,
    int rows, int scols, int dcols)
{
  int i8 = blockIdx.x * 256 + threadIdx.x;
  int c8 = dcols / 8;
  if (i8 >= rows * c8) return;
  int r = i8 / c8, c0 = (i8 % c8) * 8;
  const float* s = src + (size_t)r * scols;
  u16x8 o;
  #pragma unroll
  for (int e = 0; e < 8; e++) { int c = c0 + e; o[e] = (c < scols) ? f2bf(s[c]) : (unsigned short)0; }
  *(u16x8*)(dst + (size_t)r * dcols + c0) = o;
}

// ---------------- elementwise / reduction kernels ----------------
__global__ __launch_bounds__(256) void ynorm_kernel(
    const float* __restrict__ x, const float* __restrict__ dm,
    unsigned short* __restrict__ y, float* __restrict__ ninv, int D0)
{
  const int b = blockIdx.x, tid = threadIdx.x;
  const float4* x4 = (const float4*)(x + (size_t)b * D0);
  const float4* d4 = (const float4*)(dm + (size_t)b * D0);
  ushort4* y4 = (ushort4*)(y + (size_t)b * D0);
  const int n4 = D0 / 4;
  float ss = 0.f;
  for (int i = tid; i < n4; i += 256) {
    float4 xv = x4[i], dv = d4[i];
    ss += xv.x*xv.x + xv.y*xv.y + xv.z*xv.z + xv.w*xv.w;
    ushort4 o;
    o.x = f2bf(xv.x*dv.x); o.y = f2bf(xv.y*dv.y);
    o.z = f2bf(xv.z*dv.z); o.w = f2bf(xv.w*dv.w);
    y4[i] = o;
  }
  #pragma unroll
  for (int off = 32; off > 0; off >>= 1) ss += __shfl_down(ss, off);
  __shared__ float wsum[4];
  if ((tid & 63) == 0) wsum[tid >> 6] = ss;
  __syncthreads();
  if (tid == 0) {
    float t = wsum[0] + wsum[1] + wsum[2] + wsum[3];
    ninv[b] = 1.0f / fmaxf(sqrtf(t), 1e-12f);
  }
}

__global__ __launch_bounds__(256) void stats_kernel(
    const float* __restrict__ proj, const int* __restrict__ ids,
    const float* __restrict__ bi, const float* __restrict__ eps,
    float* __restrict__ prior, int T)
{
  const int b = blockIdx.x, l = threadIdx.x;
  __shared__ int sid[256];
  if (l < T) sid[l] = ids[b * T + l];
  __syncthreads();
  float s1 = 0.f, s2 = 0.f;
  #pragma unroll 4
  for (int t = 0; t < T; t++) {
    float p = proj[(size_t)sid[t] * 256 + l];
    s1 += p; s2 += p * p;
  }
  float var = fmaxf((s2 - s1 * s1 / (float)T) / (float)(T - 1), 0.f);
  float dev = sqrtf(var);
  float mean = s1 / (float)T + bi[l];
  prior[b * 256 + l] = mean + sqrtf(dev) * eps[b * 256 + l];
}

__global__ __launch_bounds__(256) void epi1_kernel(
    const float* __restrict__ C1, const float* __restrict__ ninv,
    const float* __restrict__ be1, unsigned short* __restrict__ h)
{
  int i = blockIdx.x * 256 + threadIdx.x;
  int b = i >> 10, n = i & 1023;
  h[i] = f2bf(tanhf(ninv[b] * C1[i] + be1[n]));
}

__global__ __launch_bounds__(256) void z_kernel(
    const float* __restrict__ gp, const float* __restrict__ prior,
    const float* __restrict__ be2,
    float* __restrict__ out_mu, float* __restrict__ out_lv,
    unsigned short* __restrict__ z)
{
  int i = blockIdx.x * 256 + threadIdx.x;
  int b = i >> 8, l = i & 255;
  float mu = gp[b * 512 + l]       + be2[l];
  float lv = gp[b * 512 + 256 + l] + be2[256 + l];
  out_mu[i] = mu;
  out_lv[i] = lv;
  z[i] = f2bf(prior[i] * expf(0.5f * lv) + mu);
}

extern "C" void kernel_launch(void* const* d_in, const int* in_sizes, int n_in,
                              void* d_out, int out_size, void* d_ws, size_t ws_size,
                              hipStream_t stream)
{
  const float* x     = (const float*)d_in[0];
  const int*   ids   = (const int*)  d_in[1];
  const float* embed = (const float*)d_in[2];
  const float* Wi    = (const float*)d_in[3];
  const float* bi    = (const float*)d_in[4];
  const float* We1   = (const float*)d_in[5];
  const float* be1   = (const float*)d_in[6];
  const float* We2   = (const float*)d_in[7];
  const float* be2   = (const float*)d_in[8];
  const float* Wd1   = (const float*)d_in[9];
  const float* bd1   = (const float*)d_in[10];
  const float* Wd2   = (const float*)d_in[11];
  const float* bd2   = (const float*)d_in[12];
  const float* dm    = (const float*)d_in[13];
  const float* eps   = (const float*)d_in[14];

  constexpr int B = 512, T = 200, V = 3356, E = 1128, Ep = 1152, D0 = 20000, H = 1024, L = 256;

  char* w = (char*)d_ws;
  auto carve = [&](size_t bytes) { char* p = w; w += (bytes + 255) & ~(size_t)255; return p; };
  unsigned short* We1b  = (unsigned short*)carve((size_t)H * D0 * 2);   // 41 MB
  unsigned short* Wd2b  = (unsigned short*)carve((size_t)D0 * H * 2);   // 41 MB
  unsigned short* We2b  = (unsigned short*)carve((size_t)2 * L * H * 2);
  unsigned short* Wd1b  = (unsigned short*)carve((size_t)H * L * 2);
  unsigned short* embedb= (unsigned short*)carve((size_t)V * Ep * 2);   // 7.7 MB
  unsigned short* Wib   = (unsigned short*)carve((size_t)L * Ep * 2);
  float*          proj  = (float*)         carve((size_t)V * L * 4);    // 3.4 MB
  unsigned short* y     = (unsigned short*)carve((size_t)B * D0 * 2);   // 20.5 MB
  float*          C1    = (float*)         carve((size_t)B * H * 4);
  unsigned short* h     = (unsigned short*)carve((size_t)B * H * 2);
  float*          gp    = (float*)         carve((size_t)B * 2 * L * 4);
  float*          prior = (float*)         carve((size_t)B * L * 4);
  unsigned short* z     = (unsigned short*)carve((size_t)B * L * 2);
  unsigned short* hd    = (unsigned short*)carve((size_t)B * H * 2);
  float*          ninv  = (float*)         carve((size_t)B * 4);

  float* out_recon = (float*)d_out;
  float* out_mu    = out_recon + (size_t)B * D0;
  float* out_lv    = out_mu + (size_t)B * L;

  // weights -> bf16 (one fused grid-stride pass, 16 elems/thread)
  {
    const int n0 = H * D0, n1 = D0 * H, n2 = 2 * L * H, n3 = H * L;
    const int nunits16 = (n0 + n1 + n2 + n3) / 16;
    cvt4_kernel<<<2048, 256, 0, stream>>>(We1, We1b, n0, Wd2, Wd2b, n1,
                                          We2, We2b, n2, Wd1, Wd1b, n3, nunits16);
  }
  cvtpad_kernel<<<(V * (Ep/8) + 255) / 256, 256, 0, stream>>>(embed, embedb, V, E, Ep);
  cvtpad_kernel<<<(L * (Ep/8) + 255) / 256, 256, 0, stream>>>(Wi, Wib, L, E, Ep);

  // y = bf16(x*dm), ninv = 1/||x||
  ynorm_kernel<<<B, 256, 0, stream>>>(x, dm, y, ninv, D0);

  // proj = embedb @ Wib^T  (M=3356, N=256, K=1152), split-K=4
  hipMemsetAsync(proj, 0, (size_t)V * L * 4, stream);
  gemm_bf<1><<<dim3(2, 27, 4), 256, 0, stream>>>(
      embedb, Wib, nullptr, proj, nullptr, V, L, Ep, 288);
  // prior from gathered stats (adds bi)
  stats_kernel<<<B, 256, 0, stream>>>(proj, ids, bi, eps, prior, T);

  // GEMM1: C1 = y @ We1b^T  (M=512, N=1024, K=20000), split-K=25
  hipMemsetAsync(C1, 0, (size_t)B * H * 4, stream);
  gemm_bf<1><<<dim3(8, 4, 25), 256, 0, stream>>>(
      y, We1b, nullptr, C1, nullptr, B, H, D0, 800);
  // h = tanh(ninv*C1 + be1)
  epi1_kernel<<<(B * H) / 256, 256, 0, stream>>>(C1, ninv, be1, h);

  // gparams = h @ We2b^T (+be2 in z_kernel)  (M=512, N=512, K=1024), split-K=4
  hipMemsetAsync(gp, 0, (size_t)B * 2 * L * 4, stream);
  gemm_bf<1><<<dim3(4, 4, 4), 256, 0, stream>>>(
      h, We2b, nullptr, gp, nullptr, B, 2 * L, H, 256);
  // mu/logvar out, z
  z_kernel<<<(B * L) / 256, 256, 0, stream>>>(gp, prior, be2, out_mu, out_lv, z);

  // hd = tanh(z @ Wd1b^T + bd1)  (M=512, N=1024, K=256)
  gemm_bf<2><<<dim3(8, 4, 1), 256, 0, stream>>>(
      z, Wd1b, bd1, nullptr, hd, B, H, L, 256);
  // recon = hd @ Wd2b^T + bd2   (M=512, N=20000, K=1024)
  gemm_bf<0><<<dim3(157, 4, 1), 256, 0, stream>>>(
      hd, Wd2b, bd2, out_recon, nullptr, B, D0, H, 1024);
}

// Round 15
// 273.771 us; speedup vs baseline: 1.0132x; 1.0132x over previous
//
#include <hip/hip_runtime.h>
#include <hip/hip_bf16.h>

typedef __bf16 bf16x8 __attribute__((ext_vector_type(8)));
typedef float f32x4 __attribute__((ext_vector_type(4)));
typedef unsigned short u16x8 __attribute__((ext_vector_type(8)));
typedef unsigned int u32x4 __attribute__((ext_vector_type(4)));

static __device__ __forceinline__ unsigned short f2bf(float f){
  unsigned int u = __float_as_uint(f);
  u += 0x7fffu + ((u >> 16) & 1u);   // round-to-nearest-even
  return (unsigned short)(u >> 16);
}

static __device__ __forceinline__ unsigned int cvtpk(float lo, float hi){
  unsigned int r;                     // [15:0]=bf16(lo), [31:16]=bf16(hi), RNE
  asm("v_cvt_pk_bf16_f32 %0, %1, %2" : "=v"(r) : "v"(lo), "v"(hi));
  return r;
}

static __device__ __forceinline__ u16x8 cvt8(const float4& a, const float4& b){
  u16x8 r;
  r[0]=f2bf(a.x); r[1]=f2bf(a.y); r[2]=f2bf(a.z); r[3]=f2bf(a.w);
  r[4]=f2bf(b.x); r[5]=f2bf(b.y); r[6]=f2bf(b.z); r[7]=f2bf(b.w);
  return r;
}

static __device__ __forceinline__ void gload16(const void* g, void* l){
  __builtin_amdgcn_global_load_lds(
      (const __attribute__((address_space(1))) unsigned int*)g,
      (__attribute__((address_space(3))) unsigned int*)l, 16, 0, 0);
}

// T1: XCD-aware bijective block remap (m204 variant) — r13-verified: FETCH −65%.
static __device__ __forceinline__ int xcd_remap(int o, int nwg){
  const int NX = 8;
  int q = nwg / NX, r = nwg % NX;
  int xcd = o % NX, pos = o / NX;
  return (xcd < r ? xcd * (q + 1) : r * (q + 1) + (xcd - r) * q) + pos;
}

// ============ big GEMM, fp32-B direct (r11-verified) + T1 remap ======================
// C[m,n] = epi( sum_k A[m,k](bf16) * B[n,k](fp32) ), K mult of 32. 128x128, BK=32.
// Triple-buffer, stage t+3 into vacated buffer, counted vmcnt(12/6/0).
// B staged RAW fp32 via gload16 with PRE-SWIZZLED source (granule (lane&7)^(lane>>3));
// frag-read unswizzles (slot (2fq)^(r&7), ^1) -> 2 lanes/slot, conflict-free;
// fp32->bf16 at frag-build via v_cvt_pk_bf16_f32 (RNE == f2bf, bit-identical).
// EPI 0: Cf=acc+bias  EPI 1: atomicAdd  EPI 2: Cbf=bf16(tanh(acc+bias))
template<int EPI>
__global__ __launch_bounds__(256, 2) void gemm_bigf(
    const unsigned short* __restrict__ A, const float* __restrict__ Bw,
    const float* __restrict__ bias,
    float* __restrict__ Cf, unsigned short* __restrict__ Cbf,
    int M, int N, int K, int kchunk)
{
  constexpr int BK = 32, BUFB = 8192 + 16384;          // A 8KB bf16 + B 16KB fp32
  __shared__ char smem[3 * BUFB];                      // 72KB

  // T1 remap
  const int gx = gridDim.x, gy = gridDim.y;
  const int nwg = gx * gy * gridDim.z;
  int o = blockIdx.x + gx * (blockIdx.y + gy * blockIdx.z);
  int vv = xcd_remap(o, nwg);
  const int bxi = vv % gx; vv /= gx;
  const int byi = vv % gy; const int bzi = vv / gy;

  const int tid  = threadIdx.x, lane = tid & 63, wave = tid >> 6;
  const int bm0  = byi * 128, bn0 = bxi * 128;
  const int k0   = bzi * kchunk;
  const int kend = min(K, k0 + kchunk);                // kchunk mult of 32
  const int nk   = (kend - k0) / BK;
  const int fr = lane & 15, fq = lane >> 4;
  const int wm = (wave >> 1) * 64, wn = (wave & 1) * 64;

  // A: call c, wave w -> rows c*64 + w*16 + (lane>>2), col unit (lane&3)*8 bf16
  const int ar_off = wave * 16 + (lane >> 2), ac_off = (lane & 3) * 8;
  // B: call c, wave w -> rows c*32 + w*8 + (lane>>3), source granule (lane&7)^(lane>>3)
  const int br_off = wave * 8 + (lane >> 3);
  const int bg_off = (((lane & 7) ^ (lane >> 3)) << 2);   // float offset of granule

  auto stage = [&](int buf, int t){
    char* base = smem + buf * BUFB;
    const int kk = k0 + t * BK;
    #pragma unroll
    for (int c = 0; c < 2; c++) {
      const int r = min(bm0 + c * 64 + ar_off, M - 1);
      gload16(A + (size_t)r * K + kk + ac_off, base + c * 4096 + wave * 1024);
    }
    #pragma unroll
    for (int c = 0; c < 4; c++) {
      const int r = min(bn0 + c * 32 + br_off, N - 1);
      gload16(Bw + (size_t)r * K + kk + bg_off, base + 8192 + c * 4096 + wave * 1024);
    }
  };

  stage(0, 0);
  if (nk > 1) stage(1, 1);
  if (nk > 2) stage(2, 2);

  f32x4 acc[4][4] = {};
  int cur = 0;

  for (int t = 0; t < nk; ++t) {
    const int rem = nk - t - 1;
    if (rem >= 2)      asm volatile("s_waitcnt vmcnt(12)" ::: "memory");
    else if (rem == 1) asm volatile("s_waitcnt vmcnt(6)"  ::: "memory");
    else               asm volatile("s_waitcnt vmcnt(0)"  ::: "memory");
    __builtin_amdgcn_s_barrier();                      // tile t visible to all waves
    __builtin_amdgcn_sched_barrier(0);

    const unsigned short* lA = (const unsigned short*)(smem + cur * BUFB);
    const char*           lB = smem + cur * BUFB + 8192;
    u16x8 af[4], bg[4];
    #pragma unroll
    for (int i = 0; i < 4; i++) af[i] = *(const u16x8*)&lA[(wm + i*16 + fr) * BK + fq * 8];
    #pragma unroll
    for (int j = 0; j < 4; j++) {
      const int r  = wn + j*16 + fr;
      const int s0 = (((fq << 1) ^ (r & 7)) << 4);     // byte slot of granule 2fq
      const char* bp = lB + r * 128;
      f32x4 u = *(const f32x4*)(bp + s0);              // floats 8fq..8fq+3
      f32x4 v = *(const f32x4*)(bp + (s0 ^ 16));       // floats 8fq+4..8fq+7
      u32x4 wv; wv[0]=cvtpk(u[0],u[1]); wv[1]=cvtpk(u[2],u[3]);
                wv[2]=cvtpk(v[0],v[1]); wv[3]=cvtpk(v[2],v[3]);
      bg[j] = __builtin_bit_cast(u16x8, wv);
    }
    asm volatile("s_waitcnt lgkmcnt(0)" ::: "memory"); // my reads in regs
    __builtin_amdgcn_sched_barrier(0);
    __builtin_amdgcn_s_barrier();                      // all waves done with buf cur
    if (t + 3 < nk) stage(cur, t + 3);                 // refill vacated buffer (DMA ∥ MFMA)

    #pragma unroll
    for (int i = 0; i < 4; i++)
      #pragma unroll
      for (int j = 0; j < 4; j++)
        acc[i][j] = __builtin_amdgcn_mfma_f32_16x16x32_bf16(
            __builtin_bit_cast(bf16x8, af[i]),
            __builtin_bit_cast(bf16x8, bg[j]),
            acc[i][j], 0, 0, 0);
    cur = (cur == 2) ? 0 : cur + 1;
  }

  #pragma unroll
  for (int i = 0; i < 4; i++)
    #pragma unroll
    for (int j = 0; j < 4; j++)
      #pragma unroll
      for (int r = 0; r < 4; r++) {
        int row = bm0 + wm + i*16 + fq*4 + r;
        int col = bn0 + wn + j*16 + fr;
        if (row < M && col < N) {
          float v2 = acc[i][j][r];
          if constexpr (EPI == 0) {
            Cf[(size_t)row * N + col] = v2 + (bias ? bias[col] : 0.0f);
          } else if constexpr (EPI == 1) {
            atomicAdd(&Cf[(size_t)row * N + col], v2);
          } else {
            Cbf[(size_t)row * N + col] = f2bf(tanhf(v2 + bias[col]));
          }
        }
      }
}

// ---------------- bf16 GEMM (r14): 128x128, triple-buffer, counted vmcnt, T1 -------
template<int EPI>
__global__ __launch_bounds__(256) void gemm_bf(
    const unsigned short* __restrict__ A, const unsigned short* __restrict__ Bw,
    const float* __restrict__ bias,
    float* __restrict__ Cf, unsigned short* __restrict__ Cbf,
    int M, int N, int K, int kchunk)
{
  constexpr int BM = 128, BN = 128, BK = 32, BUF = (BM + BN) * BK;
  __shared__ unsigned short lds[3 * BUF];             // 3 x 16 KB

  const int gx = gridDim.x, gy = gridDim.y;
  const int nwg = gx * gy * gridDim.z;
  int o = blockIdx.x + gx * (blockIdx.y + gy * blockIdx.z);
  int v = xcd_remap(o, nwg);
  const int bx = v % gx; v /= gx;
  const int by = v % gy; const int bz = v / gy;

  const int tid  = threadIdx.x, lane = tid & 63, wave = tid >> 6;
  const int bm0  = by * BM, bn0 = bx * BN;
  const int k0   = bz * kchunk;
  const int kend = min(K, k0 + kchunk);
  const int fr = lane & 15, fq = lane >> 4;
  const int wm = (wave >> 1) * 64, wn = (wave & 1) * 64;

  const bool isA  = wave < 2;
  const int cbase = (wave & 1) * 4;
  const int srow  = lane >> 2, scol = (lane & 3) * 8;
  const unsigned short* G = isA ? A : Bw;
  const int glim = (isA ? M : N) - 1;
  const int g0   = isA ? bm0 : bn0;
  const int loff = isA ? 0 : BM * BK;

  const int nk = (kend - k0) / BK;

  auto stage = [&](int buf, int t){
    unsigned short* dst = lds + buf * BUF + loff;
    const int kk = k0 + t * BK;
    #pragma unroll
    for (int c = 0; c < 4; c++) {
      const int ch = cbase + c;
      const int r = min(g0 + ch * 16 + srow, glim);
      gload16(G + (size_t)r * K + kk + scol, (char*)dst + ch * 1024);
    }
  };

  if (nk > 0) stage(0, 0);
  if (nk > 1) stage(1, 1);
  if (nk > 2) stage(2, 2);

  f32x4 acc[4][4] = {};
  int cur = 0;

  for (int t = 0; t < nk; ++t) {
    const int rem = nk - t - 1;
    if (rem >= 2)      asm volatile("s_waitcnt vmcnt(8)" ::: "memory");
    else if (rem == 1) asm volatile("s_waitcnt vmcnt(4)" ::: "memory");
    else               asm volatile("s_waitcnt vmcnt(0)" ::: "memory");
    __builtin_amdgcn_s_barrier();
    __builtin_amdgcn_sched_barrier(0);

    const unsigned short* lA = lds + cur * BUF;
    const unsigned short* lB = lA + BM * BK;
    u16x8 af[4], bg[4];
    #pragma unroll
    for (int i = 0; i < 4; i++) af[i] = *(const u16x8*)&lA[(wm + i*16 + fr) * BK + fq * 8];
    #pragma unroll
    for (int j = 0; j < 4; j++) bg[j] = *(const u16x8*)&lB[(wn + j*16 + fr) * BK + fq * 8];

    #pragma unroll
    for (int i = 0; i < 4; i++)
      #pragma unroll
      for (int j = 0; j < 4; j++)
        acc[i][j] = __builtin_amdgcn_mfma_f32_16x16x32_bf16(
            __builtin_bit_cast(bf16x8, af[i]),
            __builtin_bit_cast(bf16x8, bg[j]),
            acc[i][j], 0, 0, 0);

    asm volatile("s_waitcnt lgkmcnt(0)" ::: "memory");
    __builtin_amdgcn_sched_barrier(0);
    __builtin_amdgcn_s_barrier();
    if (t + 3 < nk) stage(cur, t + 3);
    cur = (cur == 2) ? 0 : cur + 1;
  }

  #pragma unroll
  for (int i = 0; i < 4; i++)
    #pragma unroll
    for (int j = 0; j < 4; j++)
      #pragma unroll
      for (int r = 0; r < 4; r++) {
        int row = bm0 + wm + i*16 + fq*4 + r;
        int col = bn0 + wn + j*16 + fr;
        if (row < M && col < N) {
          float v2 = acc[i][j][r];
          if constexpr (EPI == 0) {
            Cf[(size_t)row * N + col] = v2 + (bias ? bias[col] : 0.0f);
          } else if constexpr (EPI == 1) {
            atomicAdd(&Cf[(size_t)row * N + col], v2);
          } else {
            Cbf[(size_t)row * N + col] = f2bf(tanhf(v2 + bias[col]));
          }
        }
      }
}

// ------- fp32 -> bf16 conversion (4 flat segments), grid-stride, 16 elems/thread ------
__global__ __launch_bounds__(256) void cvt4_kernel(
    const float* __restrict__ s0, unsigned short* __restrict__ d0, int n0,
    const float* __restrict__ s1, unsigned short* __restrict__ d1, int n1,
    const float* __restrict__ s2, unsigned short* __restrict__ d2, int n2,
    const float* __restrict__ s3, unsigned short* __restrict__ d3, int n3,
    int nunits16)
{
  const int stride = gridDim.x * 256;
  for (int u = blockIdx.x * 256 + threadIdx.x; u < nunits16; u += stride) {
    int i = u * 16;
    const float* s; unsigned short* d;
    if (i < n0)              { s = s0; d = d0; }
    else if ((i -= n0) < n1) { s = s1; d = d1; }
    else if ((i -= n1) < n2) { s = s2; d = d2; }
    else                     { i -= n2; s = s3; d = d3; }
    const float4* q = (const float4*)(s + i);
    float4 a0 = q[0], a1 = q[1], a2 = q[2], a3 = q[3];
    *(u16x8*)(d + i)     = cvt8(a0, a1);
    *(u16x8*)(d + i + 8) = cvt8(a2, a3);
  }
}

// fp32 [rows][scols] -> bf16 [rows][dcols], zero-padded (dcols mult of 8)
__global__ __launch_bounds__(256) void cvtpad_kernel(
    const float* __restrict__ src, unsigned short* __restrict__ dst,
    int rows, int scols, int dcols)
{
  int i8 = blockIdx.x * 256 + threadIdx.x;
  int c8 = dcols / 8;
  if (i8 >= rows * c8) return;
  int r = i8 / c8, c0 = (i8 % c8) * 8;
  const float* s = src + (size_t)r * scols;
  u16x8 o;
  #pragma unroll
  for (int e = 0; e < 8; e++) { int c = c0 + e; o[e] = (c < scols) ? f2bf(s[c]) : (unsigned short)0; }
  *(u16x8*)(dst + (size_t)r * dcols + c0) = o;
}

// ---------------- elementwise / reduction kernels ----------------
__global__ __launch_bounds__(256) void ynorm_kernel(
    const float* __restrict__ x, const float* __restrict__ dm,
    unsigned short* __restrict__ y, float* __restrict__ ninv, int D0)
{
  const int b = blockIdx.x, tid = threadIdx.x;
  const float4* x4 = (const float4*)(x + (size_t)b * D0);
  const float4* d4 = (const float4*)(dm + (size_t)b * D0);
  ushort4* y4 = (ushort4*)(y + (size_t)b * D0);
  const int n4 = D0 / 4;
  float ss = 0.f;
  for (int i = tid; i < n4; i += 256) {
    float4 xv = x4[i], dv = d4[i];
    ss += xv.x*xv.x + xv.y*xv.y + xv.z*xv.z + xv.w*xv.w;
    ushort4 o;
    o.x = f2bf(xv.x*dv.x); o.y = f2bf(xv.y*dv.y);
    o.z = f2bf(xv.z*dv.z); o.w = f2bf(xv.w*dv.w);
    y4[i] = o;
  }
  #pragma unroll
  for (int off = 32; off > 0; off >>= 1) ss += __shfl_down(ss, off);
  __shared__ float wsum[4];
  if ((tid & 63) == 0) wsum[tid >> 6] = ss;
  __syncthreads();
  if (tid == 0) {
    float t = wsum[0] + wsum[1] + wsum[2] + wsum[3];
    ninv[b] = 1.0f / fmaxf(sqrtf(t), 1e-12f);
  }
}

__global__ __launch_bounds__(256) void stats_kernel(
    const float* __restrict__ proj, const int* __restrict__ ids,
    const float* __restrict__ bi, const float* __restrict__ eps,
    float* __restrict__ prior, int T)
{
  const int b = blockIdx.x, l = threadIdx.x;
  __shared__ int sid[256];
  if (l < T) sid[l] = ids[b * T + l];
  __syncthreads();
  float s1 = 0.f, s2 = 0.f;
  #pragma unroll 4
  for (int t = 0; t < T; t++) {
    float p = proj[(size_t)sid[t] * 256 + l];
    s1 += p; s2 += p * p;
  }
  float var = fmaxf((s2 - s1 * s1 / (float)T) / (float)(T - 1), 0.f);
  float dev = sqrtf(var);
  float mean = s1 / (float)T + bi[l];
  prior[b * 256 + l] = mean + sqrtf(dev) * eps[b * 256 + l];
}

__global__ __launch_bounds__(256) void epi1_kernel(
    const float* __restrict__ C1, const float* __restrict__ ninv,
    const float* __restrict__ be1, unsigned short* __restrict__ h)
{
  int i = blockIdx.x * 256 + threadIdx.x;
  int b = i >> 10, n = i & 1023;
  h[i] = f2bf(tanhf(ninv[b] * C1[i] + be1[n]));
}

__global__ __launch_bounds__(256) void z_kernel(
    const float* __restrict__ gp, const float* __restrict__ prior,
    const float* __restrict__ be2,
    float* __restrict__ out_mu, float* __restrict__ out_lv,
    unsigned short* __restrict__ z)
{
  int i = blockIdx.x * 256 + threadIdx.x;
  int b = i >> 8, l = i & 255;
  float mu = gp[b * 512 + l]       + be2[l];
  float lv = gp[b * 512 + 256 + l] + be2[256 + l];
  out_mu[i] = mu;
  out_lv[i] = lv;
  z[i] = f2bf(prior[i] * expf(0.5f * lv) + mu);
}

extern "C" void kernel_launch(void* const* d_in, const int* in_sizes, int n_in,
                              void* d_out, int out_size, void* d_ws, size_t ws_size,
                              hipStream_t stream)
{
  const float* x     = (const float*)d_in[0];
  const int*   ids   = (const int*)  d_in[1];
  const float* embed = (const float*)d_in[2];
  const float* Wi    = (const float*)d_in[3];
  const float* bi    = (const float*)d_in[4];
  const float* We1   = (const float*)d_in[5];
  const float* be1   = (const float*)d_in[6];
  const float* We2   = (const float*)d_in[7];
  const float* be2   = (const float*)d_in[8];
  const float* Wd1   = (const float*)d_in[9];
  const float* bd1   = (const float*)d_in[10];
  const float* Wd2   = (const float*)d_in[11];
  const float* bd2   = (const float*)d_in[12];
  const float* dm    = (const float*)d_in[13];
  const float* eps   = (const float*)d_in[14];

  constexpr int B = 512, T = 200, V = 3356, E = 1128, Ep = 1152, D0 = 20000, H = 1024, L = 256;

  char* w = (char*)d_ws;
  auto carve = [&](size_t bytes) { char* p = w; w += (bytes + 255) & ~(size_t)255; return p; };
  unsigned short* We2b  = (unsigned short*)carve((size_t)2 * L * H * 2);
  unsigned short* Wd1b  = (unsigned short*)carve((size_t)H * L * 2);
  unsigned short* embedb= (unsigned short*)carve((size_t)V * Ep * 2);   // 7.7 MB
  unsigned short* Wib   = (unsigned short*)carve((size_t)L * Ep * 2);
  float*          proj  = (float*)         carve((size_t)V * L * 4);    // 3.4 MB
  unsigned short* y     = (unsigned short*)carve((size_t)B * D0 * 2);   // 20.5 MB
  float*          C1    = (float*)         carve((size_t)B * H * 4);
  unsigned short* h     = (unsigned short*)carve((size_t)B * H * 2);
  float*          gp    = (float*)         carve((size_t)B * 2 * L * 4);
  float*          prior = (float*)         carve((size_t)B * L * 4);
  unsigned short* z     = (unsigned short*)carve((size_t)B * L * 2);
  unsigned short* hd    = (unsigned short*)carve((size_t)B * H * 2);
  float*          ninv  = (float*)         carve((size_t)B * 4);

  float* out_recon = (float*)d_out;
  float* out_mu    = out_recon + (size_t)B * D0;
  float* out_lv    = out_mu + (size_t)B * L;

  // small weights -> bf16 (We2, Wd1 only; We1/Wd2 consumed fp32-direct in-GEMM)
  {
    const int n0 = 2 * L * H, n1 = H * L;               // 786432 elems, 49152 units
    const int nunits16 = (n0 + n1) / 16;
    cvt4_kernel<<<192, 256, 0, stream>>>(We2, We2b, n0, Wd1, Wd1b, n1,
                                         We2, We2b, 0, We2, We2b, 0, nunits16);
  }
  cvtpad_kernel<<<(V * (Ep/8) + 255) / 256, 256, 0, stream>>>(embed, embedb, V, E, Ep);
  cvtpad_kernel<<<(L * (Ep/8) + 255) / 256, 256, 0, stream>>>(Wi, Wib, L, E, Ep);

  // y = bf16(x*dm), ninv = 1/||x||
  ynorm_kernel<<<B, 256, 0, stream>>>(x, dm, y, ninv, D0);

  // proj = embedb @ Wib^T  (M=3356, N=256, K=1152), split-K=4  [bf16 kernel]
  hipMemsetAsync(proj, 0, (size_t)V * L * 4, stream);
  gemm_bf<1><<<dim3(2, 27, 4), 256, 0, stream>>>(
      embedb, Wib, nullptr, proj, nullptr, V, L, Ep, 288);
  // prior from gathered stats (adds bi)
  stats_kernel<<<B, 256, 0, stream>>>(proj, ids, bi, eps, prior, T);

  // GEMM1: C1 = y @ We1^T  (M=512, N=1024, K=20000), split-K=25, fp32-B direct + T1
  hipMemsetAsync(C1, 0, (size_t)B * H * 4, stream);
  gemm_bigf<1><<<dim3(8, 4, 25), 256, 0, stream>>>(
      y, We1, nullptr, C1, nullptr, B, H, D0, 800);
  // h = tanh(ninv*C1 + be1)
  epi1_kernel<<<(B * H) / 256, 256, 0, stream>>>(C1, ninv, be1, h);

  // gparams = h @ We2b^T (+be2 in z_kernel)  (M=512, N=512, K=1024), split-K=4
  hipMemsetAsync(gp, 0, (size_t)B * 2 * L * 4, stream);
  gemm_bf<1><<<dim3(4, 4, 4), 256, 0, stream>>>(
      h, We2b, nullptr, gp, nullptr, B, 2 * L, H, 256);
  // mu/logvar out, z
  z_kernel<<<(B * L) / 256, 256, 0, stream>>>(gp, prior, be2, out_mu, out_lv, z);

  // hd = tanh(z @ Wd1b^T + bd1)  (M=512, N=1024, K=256)
  gemm_bf<2><<<dim3(8, 4, 1), 256, 0, stream>>>(
      z, Wd1b, bd1, nullptr, hd, B, H, L, 256);
  // recon = hd @ Wd2^T + bd2   (M=512, N=20000, K=1024), fp32-B direct + T1
  gemm_bigf<0><<<dim3(157, 4, 1), 256, 0, stream>>>(
      hd, Wd2, bd2, out_recon, nullptr, B, D0, H, 1024);
}

// Round 16
// 260.325 us; speedup vs baseline: 1.0656x; 1.0517x over previous
//
#include <hip/hip_runtime.h>
#include <hip/hip_bf16.h>

typedef __bf16 bf16x8 __attribute__((ext_vector_type(8)));
typedef float f32x4 __attribute__((ext_vector_type(4)));
typedef unsigned short u16x8 __attribute__((ext_vector_type(8)));

static __device__ __forceinline__ unsigned short f2bf(float f){
  unsigned int u = __float_as_uint(f);
  u += 0x7fffu + ((u >> 16) & 1u);   // round-to-nearest-even
  return (unsigned short)(u >> 16);
}

static __device__ __forceinline__ u16x8 cvt8(const float4& a, const float4& b){
  u16x8 r;
  r[0]=f2bf(a.x); r[1]=f2bf(a.y); r[2]=f2bf(a.z); r[3]=f2bf(a.w);
  r[4]=f2bf(b.x); r[5]=f2bf(b.y); r[6]=f2bf(b.z); r[7]=f2bf(b.w);
  return r;
}

static __device__ __forceinline__ void gload16(const void* g, void* l){
  __builtin_amdgcn_global_load_lds(
      (const __attribute__((address_space(1))) unsigned int*)g,
      (__attribute__((address_space(3))) unsigned int*)l, 16, 0, 0);
}

// T1: XCD-aware bijective block remap (m204 variant) — r13-verified: FETCH −65%.
static __device__ __forceinline__ int xcd_remap(int o, int nwg){
  const int NX = 8;
  int q = nwg / NX, r = nwg % NX;
  int xcd = o % NX, pos = o / NX;
  return (xcd < r ? xcd * (q + 1) : r * (q + 1) + (xcd - r) * q) + pos;
}

// ---------------- pipelined bf16 GEMM: C[m,n] = epi( sum_k A[m,k]*B[n,k] )
// A:[M][K] bf16, B:[N][K] bf16, row-major. BM=BN=128, BK=32, 4 waves (2x2 of 64x64).
// r16 change: SINGLE barrier per K-step. 3 buffers, stage distance 2 into the buffer
// consumed at t-1. Safety: top-of-iter vmcnt(4) [own tile-t loads landed] -> s_barrier
// [all waves likewise, AND all waves' t-1 frag reads complete (their MFMAs issued,
// which required the compiler's lgkm wait)] -> staging into tile t-1's buffer is safe.
// Steady vmcnt(4): outstanding = tiles t (4 loads, must land) + t+1 (may fly).
// EPI 0: Cf = acc + bias(optional)  EPI 1: atomicAdd(Cf, acc)  EPI 2: Cbf = bf16(tanh(acc+bias))
template<int EPI>
__global__ __launch_bounds__(256) void gemm_bf(
    const unsigned short* __restrict__ A, const unsigned short* __restrict__ Bw,
    const float* __restrict__ bias,
    float* __restrict__ Cf, unsigned short* __restrict__ Cbf,
    int M, int N, int K, int kchunk)
{
  constexpr int BM = 128, BN = 128, BK = 32, BUF = (BM + BN) * BK;
  __shared__ unsigned short lds[3 * BUF];             // 3 x 16 KB

  // T1 remap: consecutive logical ids (fastest dim = x) chunked per XCD
  const int gx = gridDim.x, gy = gridDim.y;
  const int nwg = gx * gy * gridDim.z;
  int o = blockIdx.x + gx * (blockIdx.y + gy * blockIdx.z);
  int v = xcd_remap(o, nwg);
  const int bx = v % gx; v /= gx;
  const int by = v % gy; const int bz = v / gy;

  const int tid  = threadIdx.x, lane = tid & 63, wave = tid >> 6;
  const int bm0  = by * BM, bn0 = bx * BN;
  const int k0   = bz * kchunk;
  const int kend = min(K, k0 + kchunk);               // kchunk multiple of 32 everywhere
  const int fr = lane & 15, fq = lane >> 4;
  const int wm = (wave >> 1) * 64, wn = (wave & 1) * 64;

  // staging: waves 0,1 -> A chunks 0..3 / 4..7; waves 2,3 -> B likewise.
  // chunk = 1KB = 16 rows of [128][32] bf16; lane l -> dest base + l*16
  const bool isA  = wave < 2;
  const int cbase = (wave & 1) * 4;
  const int srow  = lane >> 2, scol = (lane & 3) * 8;
  const unsigned short* G = isA ? A : Bw;
  const int glim = (isA ? M : N) - 1;
  const int g0   = isA ? bm0 : bn0;
  const int loff = isA ? 0 : BM * BK;

  const int nk = (kend - k0) / BK;                    // exact (kchunk mult of 32)

  auto stage = [&](int buf, int t){
    unsigned short* dst = lds + buf * BUF + loff;
    const int kk = k0 + t * BK;
    #pragma unroll
    for (int c = 0; c < 4; c++) {
      const int ch = cbase + c;
      const int r = min(g0 + ch * 16 + srow, glim);   // clamp; epilogue masks
      gload16(G + (size_t)r * K + kk + scol, (char*)dst + ch * 1024);
    }
  };

  if (nk > 0) stage(0, 0);
  if (nk > 1) stage(1, 1);

  f32x4 acc[4][4] = {};
  int cur = 0;                                        // = t % 3

  for (int t = 0; t < nk; ++t) {
    if (t < nk - 1) asm volatile("s_waitcnt vmcnt(4)" ::: "memory");
    else            asm volatile("s_waitcnt vmcnt(0)" ::: "memory");
    __builtin_amdgcn_s_barrier();                     // tile t fully landed; t-1 reads done
    __builtin_amdgcn_sched_barrier(0);

    if (t + 2 < nk) {                                 // refill buffer freed at t-1
      int sb = cur + 2; if (sb >= 3) sb -= 3;         // (t+2) % 3
      stage(sb, t + 2);
    }

    const unsigned short* lA = lds + cur * BUF;
    const unsigned short* lB = lA + BM * BK;
    u16x8 af[4], bg[4];
    #pragma unroll
    for (int i = 0; i < 4; i++) af[i] = *(const u16x8*)&lA[(wm + i*16 + fr) * BK + fq * 8];
    #pragma unroll
    for (int j = 0; j < 4; j++) bg[j] = *(const u16x8*)&lB[(wn + j*16 + fr) * BK + fq * 8];

    #pragma unroll
    for (int i = 0; i < 4; i++)
      #pragma unroll
      for (int j = 0; j < 4; j++)
        acc[i][j] = __builtin_amdgcn_mfma_f32_16x16x32_bf16(
            __builtin_bit_cast(bf16x8, af[i]),
            __builtin_bit_cast(bf16x8, bg[j]),
            acc[i][j], 0, 0, 0);
    cur = (cur == 2) ? 0 : cur + 1;
  }

  #pragma unroll
  for (int i = 0; i < 4; i++)
    #pragma unroll
    for (int j = 0; j < 4; j++)
      #pragma unroll
      for (int r = 0; r < 4; r++) {
        int row = bm0 + wm + i*16 + fq*4 + r;
        int col = bn0 + wn + j*16 + fr;
        if (row < M && col < N) {
          float v2 = acc[i][j][r];
          if constexpr (EPI == 0) {
            Cf[(size_t)row * N + col] = v2 + (bias ? bias[col] : 0.0f);
          } else if constexpr (EPI == 1) {
            atomicAdd(&Cf[(size_t)row * N + col], v2);
          } else {
            Cbf[(size_t)row * N + col] = f2bf(tanhf(v2 + bias[col]));
          }
        }
      }
}

// ---------- cvtpad helper: fp32 [rows][scols] -> bf16 [rows][dcols], zero-padded ------
static __device__ __forceinline__ void cvtpad_body(
    const float* __restrict__ src, unsigned short* __restrict__ dst,
    int rows, int scols, int dcols, int i8)
{
  int c8 = dcols / 8;
  if (i8 >= rows * c8) return;
  int r = i8 / c8, c0 = (i8 % c8) * 8;
  const float* s = src + (size_t)r * scols;
  u16x8 o;
  #pragma unroll
  for (int e = 0; e < 8; e++) { int c = c0 + e; o[e] = (c < scols) ? f2bf(s[c]) : (unsigned short)0; }
  *(u16x8*)(dst + (size_t)r * dcols + c0) = o;
}

// ---------- merged prep: cvt4 (weights->bf16) ∥ ynorm ∥ cvtpad(embed) ∥ cvtpad(Wi) ----
// One dispatch; block ranges take different roles. Aggregates memory-level parallelism
// (cvt4 alone measured only 2.2 TB/s; the other streams overlap into its window).
__global__ __launch_bounds__(256) void prep_kernel(
    const float* __restrict__ We1, unsigned short* __restrict__ We1b,
    const float* __restrict__ Wd2, unsigned short* __restrict__ Wd2b,
    const float* __restrict__ We2, unsigned short* __restrict__ We2b,
    const float* __restrict__ Wd1, unsigned short* __restrict__ Wd1b,
    const float* __restrict__ embed, unsigned short* __restrict__ embedb,
    const float* __restrict__ Wi, unsigned short* __restrict__ Wib,
    const float* __restrict__ x, const float* __restrict__ dm,
    unsigned short* __restrict__ y, float* __restrict__ ninv)
{
  constexpr int D0 = 20000, H = 1024, L = 256, V = 3356, E = 1128, Ep = 1152;
  constexpr int n0 = H * D0, n1 = D0 * H, n2 = 2 * L * H, n3 = H * L;
  constexpr int CVT_B = 2048, YN_B = 512;
  constexpr int PE_B = (V * (Ep / 8) + 255) / 256;     // 1888
  const int bb = blockIdx.x, tid = threadIdx.x;

  if (bb < CVT_B) {
    constexpr int nunits16 = (n0 + n1 + n2 + n3) / 16;
    const int stride = CVT_B * 256;
    for (int u = bb * 256 + tid; u < nunits16; u += stride) {
      int i = u * 16;
      const float* s; unsigned short* d;
      if (i < n0)              { s = We1; d = We1b; }
      else if ((i -= n0) < n1) { s = Wd2; d = Wd2b; }
      else if ((i -= n1) < n2) { s = We2; d = We2b; }
      else                     { i -= n2; s = Wd1; d = Wd1b; }
      const float4* q = (const float4*)(s + i);
      float4 a0 = q[0], a1 = q[1], a2 = q[2], a3 = q[3];
      *(u16x8*)(d + i)     = cvt8(a0, a1);
      *(u16x8*)(d + i + 8) = cvt8(a2, a3);
    }
  } else if (bb < CVT_B + YN_B) {
    const int b = bb - CVT_B;
    const float4* x4 = (const float4*)(x + (size_t)b * D0);
    const float4* d4 = (const float4*)(dm + (size_t)b * D0);
    ushort4* y4 = (ushort4*)(y + (size_t)b * D0);
    const int n4 = D0 / 4;
    float ss = 0.f;
    for (int i = tid; i < n4; i += 256) {
      float4 xv = x4[i], dv = d4[i];
      ss += xv.x*xv.x + xv.y*xv.y + xv.z*xv.z + xv.w*xv.w;
      ushort4 ov;
      ov.x = f2bf(xv.x*dv.x); ov.y = f2bf(xv.y*dv.y);
      ov.z = f2bf(xv.z*dv.z); ov.w = f2bf(xv.w*dv.w);
      y4[i] = ov;
    }
    #pragma unroll
    for (int off = 32; off > 0; off >>= 1) ss += __shfl_down(ss, off);
    __shared__ float wsum[4];
    if ((tid & 63) == 0) wsum[tid >> 6] = ss;
    __syncthreads();
    if (tid == 0) {
      float t = wsum[0] + wsum[1] + wsum[2] + wsum[3];
      ninv[b] = 1.0f / fmaxf(sqrtf(t), 1e-12f);
    }
  } else if (bb < CVT_B + YN_B + PE_B) {
    cvtpad_body(embed, embedb, V, E, Ep, (bb - (CVT_B + YN_B)) * 256 + tid);
  } else {
    cvtpad_body(Wi, Wib, L, E, Ep, (bb - (CVT_B + YN_B + PE_B)) * 256 + tid);
  }
}

// ---------------- remaining elementwise / reduction kernels ----------------
__global__ __launch_bounds__(256) void stats_kernel(
    const float* __restrict__ proj, const int* __restrict__ ids,
    const float* __restrict__ bi, const float* __restrict__ eps,
    float* __restrict__ prior, int T)
{
  const int b = blockIdx.x, l = threadIdx.x;
  __shared__ int sid[256];
  if (l < T) sid[l] = ids[b * T + l];
  __syncthreads();
  float s1 = 0.f, s2 = 0.f;
  #pragma unroll 4
  for (int t = 0; t < T; t++) {
    float p = proj[(size_t)sid[t] * 256 + l];
    s1 += p; s2 += p * p;
  }
  float var = fmaxf((s2 - s1 * s1 / (float)T) / (float)(T - 1), 0.f);
  float dev = sqrtf(var);
  float mean = s1 / (float)T + bi[l];
  prior[b * 256 + l] = mean + sqrtf(dev) * eps[b * 256 + l];
}

__global__ __launch_bounds__(256) void epi1_kernel(
    const float* __restrict__ C1, const float* __restrict__ ninv,
    const float* __restrict__ be1, unsigned short* __restrict__ h)
{
  int i = blockIdx.x * 256 + threadIdx.x;
  int b = i >> 10, n = i & 1023;
  h[i] = f2bf(tanhf(ninv[b] * C1[i] + be1[n]));
}

__global__ __launch_bounds__(256) void z_kernel(
    const float* __restrict__ gp, const float* __restrict__ prior,
    const float* __restrict__ be2,
    float* __restrict__ out_mu, float* __restrict__ out_lv,
    unsigned short* __restrict__ z)
{
  int i = blockIdx.x * 256 + threadIdx.x;
  int b = i >> 8, l = i & 255;
  float mu = gp[b * 512 + l]       + be2[l];
  float lv = gp[b * 512 + 256 + l] + be2[256 + l];
  out_mu[i] = mu;
  out_lv[i] = lv;
  z[i] = f2bf(prior[i] * expf(0.5f * lv) + mu);
}

extern "C" void kernel_launch(void* const* d_in, const int* in_sizes, int n_in,
                              void* d_out, int out_size, void* d_ws, size_t ws_size,
                              hipStream_t stream)
{
  const float* x     = (const float*)d_in[0];
  const int*   ids   = (const int*)  d_in[1];
  const float* embed = (const float*)d_in[2];
  const float* Wi    = (const float*)d_in[3];
  const float* bi    = (const float*)d_in[4];
  const float* We1   = (const float*)d_in[5];
  const float* be1   = (const float*)d_in[6];
  const float* We2   = (const float*)d_in[7];
  const float* be2   = (const float*)d_in[8];
  const float* Wd1   = (const float*)d_in[9];
  const float* bd1   = (const float*)d_in[10];
  const float* Wd2   = (const float*)d_in[11];
  const float* bd2   = (const float*)d_in[12];
  const float* dm    = (const float*)d_in[13];
  const float* eps   = (const float*)d_in[14];

  constexpr int B = 512, T = 200, V = 3356, E = 1128, Ep = 1152, D0 = 20000, H = 1024, L = 256;

  char* w = (char*)d_ws;
  auto carve = [&](size_t bytes) { char* p = w; w += (bytes + 255) & ~(size_t)255; return p; };
  unsigned short* We1b  = (unsigned short*)carve((size_t)H * D0 * 2);   // 41 MB
  unsigned short* Wd2b  = (unsigned short*)carve((size_t)D0 * H * 2);   // 41 MB
  unsigned short* We2b  = (unsigned short*)carve((size_t)2 * L * H * 2);
  unsigned short* Wd1b  = (unsigned short*)carve((size_t)H * L * 2);
  unsigned short* embedb= (unsigned short*)carve((size_t)V * Ep * 2);   // 7.7 MB
  unsigned short* Wib   = (unsigned short*)carve((size_t)L * Ep * 2);
  float*          proj  = (float*)         carve((size_t)V * L * 4);    // 3.4 MB
  unsigned short* y     = (unsigned short*)carve((size_t)B * D0 * 2);   // 20.5 MB
  float*          C1    = (float*)         carve((size_t)B * H * 4);
  unsigned short* h     = (unsigned short*)carve((size_t)B * H * 2);
  float*          gp    = (float*)         carve((size_t)B * 2 * L * 4);
  float*          prior = (float*)         carve((size_t)B * L * 4);
  unsigned short* z     = (unsigned short*)carve((size_t)B * L * 2);
  unsigned short* hd    = (unsigned short*)carve((size_t)B * H * 2);
  float*          ninv  = (float*)         carve((size_t)B * 4);

  float* out_recon = (float*)d_out;
  float* out_mu    = out_recon + (size_t)B * D0;
  float* out_lv    = out_mu + (size_t)B * L;

  // merged prep: weights->bf16 ∥ y=bf16(x*dm)+ninv ∥ embed/Wi pad-convert
  {
    constexpr int CVT_B = 2048, YN_B = 512;
    constexpr int PE_B = (V * (Ep / 8) + 255) / 256;    // 1888
    constexpr int PW_B = (L * (Ep / 8) + 255) / 256;    // 144
    prep_kernel<<<CVT_B + YN_B + PE_B + PW_B, 256, 0, stream>>>(
        We1, We1b, Wd2, Wd2b, We2, We2b, Wd1, Wd1b,
        embed, embedb, Wi, Wib, x, dm, y, ninv);
  }

  // proj = embedb @ Wib^T  (M=3356, N=256, K=1152), split-K=4
  hipMemsetAsync(proj, 0, (size_t)V * L * 4, stream);
  gemm_bf<1><<<dim3(2, 27, 4), 256, 0, stream>>>(
      embedb, Wib, nullptr, proj, nullptr, V, L, Ep, 288);
  // prior from gathered stats (adds bi)
  stats_kernel<<<B, 256, 0, stream>>>(proj, ids, bi, eps, prior, T);

  // GEMM1: C1 = y @ We1b^T  (M=512, N=1024, K=20000), split-K=25
  hipMemsetAsync(C1, 0, (size_t)B * H * 4, stream);
  gemm_bf<1><<<dim3(8, 4, 25), 256, 0, stream>>>(
      y, We1b, nullptr, C1, nullptr, B, H, D0, 800);
  // h = tanh(ninv*C1 + be1)
  epi1_kernel<<<(B * H) / 256, 256, 0, stream>>>(C1, ninv, be1, h);

  // gparams = h @ We2b^T (+be2 in z_kernel)  (M=512, N=512, K=1024), split-K=4
  hipMemsetAsync(gp, 0, (size_t)B * 2 * L * 4, stream);
  gemm_bf<1><<<dim3(4, 4, 4), 256, 0, stream>>>(
      h, We2b, nullptr, gp, nullptr, B, 2 * L, H, 256);
  // mu/logvar out, z
  z_kernel<<<(B * L) / 256, 256, 0, stream>>>(gp, prior, be2, out_mu, out_lv, z);

  // hd = tanh(z @ Wd1b^T + bd1)  (M=512, N=1024, K=256)
  gemm_bf<2><<<dim3(8, 4, 1), 256, 0, stream>>>(
      z, Wd1b, bd1, nullptr, hd, B, H, L, 256);
  // recon = hd @ Wd2b^T + bd2   (M=512, N=20000, K=1024)
  gemm_bf<0><<<dim3(157, 4, 1), 256, 0, stream>>>(
      hd, Wd2b, bd2, out_recon, nullptr, B, D0, H, 1024);
}